// Round 7
// baseline (222.054 us; speedup 1.0000x reference)
//
#include <hip/hip_runtime.h>

// ---------------------------------------------------------------------------
// Fused LeNet forward, round 15: cut LDS traffic (fc register blocking).
//  - R14 lesson: 512thr = 8 waves, so "32 waves" was actually 16. Real
//    finding: VALU-time invariant ~40us across all configs, VALUBusy caps
//    ~48%. Model with m134 costs (b128=12cyc, b64=7): 4 SIMDs share 1 LDS
//    return path; per-block LDS ~85K cyc x2 blocks = ~71us of the 89.5us.
//    KERNEL IS LDS-BANDWIDTH-BOUND.
//  - Biggest consumer: fc1 re-reads p2 once per row (120x) = 36K cyc/block.
//    Fix: 4-row x 4-img register tiles -> each p2 b128 serves 4 rows.
//    fc1: (rowq30, kq4, imq4)=480thr, 25 f4-iters, w from global L2.
//    fc1 LDS 36K->9K. fc2 same treatment: (rowq21, imq4)=84thr: 7.5K->1.9K.
//  - scr partials: per-img [120rows][4kq] at +400 (above p2, dead xs tail);
//    reduce pass 480thr (row, imq): f4 read + hsum + bias + relu -> f1.
//  - Conv phases byte-identical to R14. conv2 W-from-global banked for next.
//  - Predict: dur 89.5 -> 60-70us, VALU -> 50-58%. If unchanged: model wrong.
// ---------------------------------------------------------------------------

typedef float v2f __attribute__((ext_vector_type(2)));
__device__ __forceinline__ v2f mk2(float a, float b) { v2f t; t.x = a; t.y = b; return t; }
__device__ __forceinline__ v2f shfl2(v2f v, int src) {
    v2f r; r.x = __shfl(v.x, src, 64); r.y = __shfl(v.y, src, 64); return r;
}

constexpr int THREADS = 512;
constexpr int IPB = 16;                // images per block (2 per wave)

// LDS layout (float offsets)
constexpr int W1P_OFF = 0;             // conv1 w packed [ocp0..2][k0..74][2] = 450
constexpr int W2P_OFF = 452;           // conv2 w packed [ocp0..7][k0..149][2] = 2400
constexpr int IMG_BASE = 2852;
// per-image offsets (region reused phase to phase):
constexpr int XS_OFF = 0;              // [3][15] rows of 20 fl (16 used) = 900
constexpr int P1_OFF = 0;              // [6][10][12] = 720 (overwrites xs)
constexpr int P2_OFF = 0;              // [400] (overwrites p1 head; wave-local dep)
constexpr int SCR_OFF = 400;           // [120][4] fc1 partials = 480, above p2
constexpr int F1_OFF = 0;              // [120] (overwrites dead p2)
constexpr int F2_OFF = 128;            // [84]
constexpr int IMG_STRIDE = 900;
constexpr int LDS_FLOATS = IMG_BASE + IPB * IMG_STRIDE;   // 17252 -> 69008 B

__device__ __forceinline__ void wave_sync() {
    asm volatile("s_waitcnt lgkmcnt(0)" ::: "memory");
}

extern "C" __global__ __launch_bounds__(THREADS, 8)
void lenet_fused(const float* __restrict__ x,
                 const float* __restrict__ w1,
                 const float* __restrict__ w2,
                 const float* __restrict__ fc1w, const float* __restrict__ fc1b,
                 const float* __restrict__ fc2w, const float* __restrict__ fc2b,
                 const float* __restrict__ fc3w, const float* __restrict__ fc3b,
                 float* __restrict__ out)
{
    __shared__ __align__(16) float lds[LDS_FLOATS];
    const int tid  = threadIdx.x;
    const int lane = tid & 63;
    const int wv   = tid >> 6;          // 0..7, owns images 2wv, 2wv+1
    const int img0 = blockIdx.x * IPB;
    const v2f zero2 = mk2(0.f, 0.f);

    // ---- stage weights, repacked oc-pair-minor (block-wide) ----
    for (int i = tid; i < 450; i += THREADS) {
        int ocp = i / 150, rem = i - ocp * 150, k = rem >> 1, h = rem & 1;
        lds[W1P_OFF + i] = w1[(2 * ocp + h) * 75 + k];
    }
    for (int i = tid; i < 2400; i += THREADS) {
        int ocp = i / 300, rem = i - ocp * 300, k = rem >> 1, h = rem & 1;
        lds[W2P_OFF + i] = w2[(2 * ocp + h) * 150 + k];
    }

    // ---- stage input patches rows 0..14, cols 0..15 into 20-fl rows ----
    float* baseA = lds + IMG_BASE + (wv * 2) * IMG_STRIDE;
    float* baseB = baseA + IMG_STRIDE;
    {
        const float4* xgA = (const float4*)(x + (size_t)(img0 + wv * 2) * 3072);
        const float4* xgB = (const float4*)(x + (size_t)(img0 + wv * 2 + 1) * 3072);
        float4* dA = (float4*)(baseA + XS_OFF);
        float4* dB = (float4*)(baseB + XS_OFF);
        for (int i = lane; i < 180; i += 64) {       // 3ch * 15r * 4(f4)
            int c = i / 60, rem = i - c * 60;
            int r = rem >> 2, c4 = rem & 3;
            int dst = c * 75 + r * 5 + c4;           // 20-fl row pitch
            int src = c * 256 + r * 8 + c4;
            dA[dst] = xgA[src];
            dB[dst] = xgB[src];
        }
    }
    __syncthreads();   // weights + staging visible

    float* p1A = baseA + P1_OFF;
    float* p1B = baseB + P1_OFF;

    // ---- conv1 + relu + pool1 -> p1 [6][10][12], both images ----
    {
        const int l   = (lane < 33) ? lane : 32;
        const int ocp = l / 11;
        const int r   = l - ocp * 11;
        const float4* xsA = (const float4*)(baseA + XS_OFF);
        const float4* xsB = (const float4*)(baseB + XS_OFF);
        const v2f* w1p = (const v2f*)(lds + W1P_OFF);

        v2f accA[11], accB[11];
        #pragma unroll
        for (int c = 0; c < 11; ++c) { accA[c] = zero2; accB[c] = zero2; }

        #pragma unroll
        for (int i = 0; i < 15; ++i) {
            const int ci = i / 5, kr = i - ci * 5;
            const int b = ci * 75 + (r + kr) * 5;    // 20-fl rows: 5 f4 pitch
            float4 A0 = xsA[b], A1 = xsA[b + 1], A2 = xsA[b + 2], A3 = xsA[b + 3];
            float4 B0 = xsB[b], B1 = xsB[b + 1], B2 = xsB[b + 2], B3 = xsB[b + 3];
            v2f W[5];
            #pragma unroll
            for (int kc = 0; kc < 5; ++kc) W[kc] = w1p[ocp * 75 + i * 5 + kc];
            float xa[16], xb[16];
            xa[0]=A0.x; xa[1]=A0.y; xa[2]=A0.z;  xa[3]=A0.w;
            xa[4]=A1.x; xa[5]=A1.y; xa[6]=A1.z;  xa[7]=A1.w;
            xa[8]=A2.x; xa[9]=A2.y; xa[10]=A2.z; xa[11]=A2.w;
            xa[12]=A3.x; xa[13]=A3.y; xa[14]=A3.z; xa[15]=A3.w;
            xb[0]=B0.x; xb[1]=B0.y; xb[2]=B0.z;  xb[3]=B0.w;
            xb[4]=B1.x; xb[5]=B1.y; xb[6]=B1.z;  xb[7]=B1.w;
            xb[8]=B2.x; xb[9]=B2.y; xb[10]=B2.z; xb[11]=B2.w;
            xb[12]=B3.x; xb[13]=B3.y; xb[14]=B3.z; xb[15]=B3.w;
            #pragma unroll
            for (int kc = 0; kc < 5; ++kc) {
                #pragma unroll
                for (int c = 0; c < 11; ++c) {
                    accA[c] = __builtin_elementwise_fma(
                        mk2(xa[c + kc], xa[c + kc]), W[kc], accA[c]);
                    accB[c] = __builtin_elementwise_fma(
                        mk2(xb[c + kc], xb[c + kc]), W[kc], accB[c]);
                }
            }
        }

        v2f pmA[10], pmB[10], mA[10], mB[10];
        #pragma unroll
        for (int c = 0; c < 10; ++c) {
            v2f aA0 = __builtin_elementwise_max(accA[c], zero2);
            v2f aA1 = __builtin_elementwise_max(accA[c + 1], zero2);
            pmA[c] = __builtin_elementwise_max(aA0, aA1);
            v2f aB0 = __builtin_elementwise_max(accB[c], zero2);
            v2f aB1 = __builtin_elementwise_max(accB[c + 1], zero2);
            pmB[c] = __builtin_elementwise_max(aB0, aB1);
        }
        #pragma unroll
        for (int c = 0; c < 10; ++c) {
            mA[c] = __builtin_elementwise_max(pmA[c], shfl2(pmA[c], lane + 1));
            mB[c] = __builtin_elementwise_max(pmB[c], shfl2(pmB[c], lane + 1));
        }
        wave_sync();   // xs reads drained before overwriting region with p1
        if (r < 10) {
            const int oc0 = ocp * 2;
            float2* dA0 = (float2*)(p1A + oc0 * 120 + r * 12);
            float2* dA1 = (float2*)(p1A + (oc0 + 1) * 120 + r * 12);
            float2* dB0 = (float2*)(p1B + oc0 * 120 + r * 12);
            float2* dB1 = (float2*)(p1B + (oc0 + 1) * 120 + r * 12);
            #pragma unroll
            for (int j = 0; j < 5; ++j) {
                dA0[j] = make_float2(mA[2 * j].x, mA[2 * j + 1].x);
                dA1[j] = make_float2(mA[2 * j].y, mA[2 * j + 1].y);
                dB0[j] = make_float2(mB[2 * j].x, mB[2 * j + 1].x);
                dB1[j] = make_float2(mB[2 * j].y, mB[2 * j + 1].y);
            }
        }
    }
    wave_sync();

    // ---- conv2 + relu + pool2 -> p2 [16*5*5] flatten order, both images ----
    float* p2A = baseA + P2_OFF;
    float* p2B = baseB + P2_OFF;
    {
        const int l   = (lane < 48) ? lane : 47;
        const int ocp = l / 6;
        const int r   = l - ocp * 6;
        const float4* pA4 = (const float4*)p1A;
        const float2* pA2 = (const float2*)p1A;
        const float4* pB4 = (const float4*)p1B;
        const float2* pB2 = (const float2*)p1B;
        const v2f* w2p = (const v2f*)(lds + W2P_OFF);

        v2f accA[6], accB[6];
        #pragma unroll
        for (int c = 0; c < 6; ++c) { accA[c] = zero2; accB[c] = zero2; }

        #pragma unroll
        for (int i = 0; i < 30; ++i) {
            const int ci = i / 5, kr = i - ci * 5;
            float4 A0 = pA4[ci * 30 + (r + kr) * 3 + 0];
            float4 A1 = pA4[ci * 30 + (r + kr) * 3 + 1];
            float2 A2 = pA2[ci * 60 + (r + kr) * 6 + 4];
            float4 B0 = pB4[ci * 30 + (r + kr) * 3 + 0];
            float4 B1 = pB4[ci * 30 + (r + kr) * 3 + 1];
            float2 B2 = pB2[ci * 60 + (r + kr) * 6 + 4];
            v2f W[5];
            #pragma unroll
            for (int kc = 0; kc < 5; ++kc) W[kc] = w2p[ocp * 150 + i * 5 + kc];
            float xa[10], xb[10];
            xa[0]=A0.x; xa[1]=A0.y; xa[2]=A0.z; xa[3]=A0.w;
            xa[4]=A1.x; xa[5]=A1.y; xa[6]=A1.z; xa[7]=A1.w;
            xa[8]=A2.x; xa[9]=A2.y;
            xb[0]=B0.x; xb[1]=B0.y; xb[2]=B0.z; xb[3]=B0.w;
            xb[4]=B1.x; xb[5]=B1.y; xb[6]=B1.z; xb[7]=B1.w;
            xb[8]=B2.x; xb[9]=B2.y;
            #pragma unroll
            for (int kc = 0; kc < 5; ++kc) {
                #pragma unroll
                for (int c = 0; c < 6; ++c) {
                    accA[c] = __builtin_elementwise_fma(
                        mk2(xa[c + kc], xa[c + kc]), W[kc], accA[c]);
                    accB[c] = __builtin_elementwise_fma(
                        mk2(xb[c + kc], xb[c + kc]), W[kc], accB[c]);
                }
            }
        }

        v2f pmA[5], pmB[5], mA[5], mB[5];
        #pragma unroll
        for (int c = 0; c < 5; ++c) {
            v2f aA0 = __builtin_elementwise_max(accA[c], zero2);
            v2f aA1 = __builtin_elementwise_max(accA[c + 1], zero2);
            pmA[c] = __builtin_elementwise_max(aA0, aA1);
            v2f aB0 = __builtin_elementwise_max(accB[c], zero2);
            v2f aB1 = __builtin_elementwise_max(accB[c + 1], zero2);
            pmB[c] = __builtin_elementwise_max(aB0, aB1);
        }
        #pragma unroll
        for (int c = 0; c < 5; ++c) {
            mA[c] = __builtin_elementwise_max(pmA[c], shfl2(pmA[c], lane + 1));
            mB[c] = __builtin_elementwise_max(pmB[c], shfl2(pmB[c], lane + 1));
        }
        wave_sync();   // p1 reads drained before overwriting head with p2
        if (r < 5) {
            const int oc0 = ocp * 2;
            #pragma unroll
            for (int c = 0; c < 5; ++c) {
                p2A[oc0 * 25 + r * 5 + c]       = mA[c].x;
                p2A[(oc0 + 1) * 25 + r * 5 + c] = mA[c].y;
                p2B[oc0 * 25 + r * 5 + c]       = mB[c].x;
                p2B[(oc0 + 1) * 25 + r * 5 + c] = mB[c].y;
            }
        }
    }
    __syncthreads();   // all 16 images' p2 ready

    // ---- fc1 (120x400): 480 thr = (rowq 30, kq 4, imq 4) ----
    // 4-row x 4-img register tile: each p2 b128 serves 4 rows (LDS 36K->9K).
    // w from global (L2). Partials -> scr[row][kq] per image.
    if (tid < 480) {
        const int rq  = tid >> 4;          // 0..29
        const int kq  = (tid >> 2) & 3;    // 0..3
        const int imq = tid & 3;           // 0..3
        const float4* ap0 = (const float4*)(lds + IMG_BASE + (imq * 4 + 0) * IMG_STRIDE + P2_OFF) + kq * 25;
        const float4* ap1 = (const float4*)(lds + IMG_BASE + (imq * 4 + 1) * IMG_STRIDE + P2_OFF) + kq * 25;
        const float4* ap2 = (const float4*)(lds + IMG_BASE + (imq * 4 + 2) * IMG_STRIDE + P2_OFF) + kq * 25;
        const float4* ap3 = (const float4*)(lds + IMG_BASE + (imq * 4 + 3) * IMG_STRIDE + P2_OFF) + kq * 25;
        const float* wb = fc1w + (rq * 4) * 400 + kq * 100;
        float acc[4][4];
        #pragma unroll
        for (int q = 0; q < 4; ++q)
            #pragma unroll
            for (int s = 0; s < 4; ++s) acc[q][s] = 0.f;
        for (int j = 0; j < 25; ++j) {
            float4 a0 = ap0[j], a1 = ap1[j], a2 = ap2[j], a3 = ap3[j];
            #pragma unroll
            for (int s = 0; s < 4; ++s) {
                float4 w4 = *(const float4*)(wb + s * 400 + j * 4);
                acc[0][s] += a0.x*w4.x + a0.y*w4.y + a0.z*w4.z + a0.w*w4.w;
                acc[1][s] += a1.x*w4.x + a1.y*w4.y + a1.z*w4.z + a1.w*w4.w;
                acc[2][s] += a2.x*w4.x + a2.y*w4.y + a2.z*w4.z + a2.w*w4.w;
                acc[3][s] += a3.x*w4.x + a3.y*w4.y + a3.z*w4.z + a3.w*w4.w;
            }
        }
        #pragma unroll
        for (int q = 0; q < 4; ++q)
            #pragma unroll
            for (int s = 0; s < 4; ++s)
                lds[IMG_BASE + (imq * 4 + q) * IMG_STRIDE + SCR_OFF + (rq * 4 + s) * 4 + kq] = acc[q][s];
    }
    __syncthreads();

    // ---- fc1 reduce + bias + relu -> f1: 480 thr = (row 120, imq 4) ----
    if (tid < 480) {
        const int row = tid >> 2;          // 0..119
        const int imq = tid & 3;
        const float b = fc1b[row];
        #pragma unroll
        for (int q = 0; q < 4; ++q) {
            const int im = imq * 4 + q;
            float4 s4 = *(const float4*)(lds + IMG_BASE + im * IMG_STRIDE + SCR_OFF + row * 4);
            float v = (s4.x + s4.y) + (s4.z + s4.w) + b;
            lds[IMG_BASE + im * IMG_STRIDE + F1_OFF + row] = fmaxf(v, 0.f);
        }
    }
    __syncthreads();

    // ---- fc2 (84x120): 84 thr = (rowq 21, imq 4), 4-row x 4-img tiles ----
    if (tid < 84) {
        const int rq  = tid >> 2;          // 0..20
        const int imq = tid & 3;
        const float4* fp0 = (const float4*)(lds + IMG_BASE + (imq * 4 + 0) * IMG_STRIDE + F1_OFF);
        const float4* fp1 = (const float4*)(lds + IMG_BASE + (imq * 4 + 1) * IMG_STRIDE + F1_OFF);
        const float4* fp2 = (const float4*)(lds + IMG_BASE + (imq * 4 + 2) * IMG_STRIDE + F1_OFF);
        const float4* fp3 = (const float4*)(lds + IMG_BASE + (imq * 4 + 3) * IMG_STRIDE + F1_OFF);
        const float* wb = fc2w + (rq * 4) * 120;
        float acc[4][4];
        #pragma unroll
        for (int q = 0; q < 4; ++q)
            #pragma unroll
            for (int s = 0; s < 4; ++s) acc[q][s] = 0.f;
        for (int j = 0; j < 30; ++j) {
            float4 a0 = fp0[j], a1 = fp1[j], a2 = fp2[j], a3 = fp3[j];
            #pragma unroll
            for (int s = 0; s < 4; ++s) {
                float4 w4 = *(const float4*)(wb + s * 120 + j * 4);
                acc[0][s] += a0.x*w4.x + a0.y*w4.y + a0.z*w4.z + a0.w*w4.w;
                acc[1][s] += a1.x*w4.x + a1.y*w4.y + a1.z*w4.z + a1.w*w4.w;
                acc[2][s] += a2.x*w4.x + a2.y*w4.y + a2.z*w4.z + a2.w*w4.w;
                acc[3][s] += a3.x*w4.x + a3.y*w4.y + a3.z*w4.z + a3.w*w4.w;
            }
        }
        #pragma unroll
        for (int s = 0; s < 4; ++s) {
            const float bz = fc2b[rq * 4 + s];
            #pragma unroll
            for (int q = 0; q < 4; ++q)
                lds[IMG_BASE + (imq * 4 + q) * IMG_STRIDE + F2_OFF + rq * 4 + s] =
                    fmaxf(acc[q][s] + bz, 0.f);
        }
    }
    __syncthreads();

    // ---- fc3 (10x84) -> out, 16 images x 10 rows = 160 threads ----
    if (tid < 160) {
        const int im  = tid / 10;
        const int row = tid - im * 10;
        const float4* wrow = (const float4*)(fc3w + row * 84);
        const float4* f2 = (const float4*)(lds + IMG_BASE + im * IMG_STRIDE + F2_OFF);
        v2f acc = zero2;
        #pragma unroll
        for (int k = 0; k < 21; ++k) {
            float4 w4 = wrow[k];
            float4 a = f2[k];
            acc = __builtin_elementwise_fma(mk2(a.x, a.y), mk2(w4.x, w4.y), acc);
            acc = __builtin_elementwise_fma(mk2(a.z, a.w), mk2(w4.z, w4.w), acc);
        }
        out[(size_t)(img0 + im) * 10 + row] = acc.x + acc.y + fc3b[row];
    }
}

extern "C" void kernel_launch(void* const* d_in, const int* in_sizes, int n_in,
                              void* d_out, int out_size, void* d_ws, size_t ws_size,
                              hipStream_t stream) {
    const float* x    = (const float*)d_in[0];
    const float* w1   = (const float*)d_in[1];
    const float* w2   = (const float*)d_in[2];
    const float* fc1w = (const float*)d_in[3];
    const float* fc1b = (const float*)d_in[4];
    const float* fc2w = (const float*)d_in[5];
    const float* fc2b = (const float*)d_in[6];
    const float* fc3w = (const float*)d_in[7];
    const float* fc3b = (const float*)d_in[8];
    float* out = (float*)d_out;

    const int B = in_sizes[0] / 3072;       // 8192
    const int grid = B / IPB;               // 512
    lenet_fused<<<grid, THREADS, 0, stream>>>(x, w1, w2, fc1w, fc1b,
                                              fc2w, fc2b, fc3w, fc3b, out);
}

// Round 8
// 211.194 us; speedup vs baseline: 1.0514x; 1.0514x over previous
//
#include <hip/hip_runtime.h>

// ---------------------------------------------------------------------------
// Fused LeNet forward, round 16: R10 (84us best) + wide-LDS conv reads.
//  - R15 killed the "fc LDS bytes" theory (cut them, got slower: conflict
//    + scatter overheads). Surviving model: per-CU LDS pipe, ~7-12cyc per
//    wave-instruction (m134); R14's ~21K LDS instr/CU ~= 75us of its 89.5.
//    => cut LDS INSTRUCTION COUNT with wide loads, zero layout risk.
//  - Base: R10 kernel verbatim (512thr, IPB=8, 1 img/wave, bounds(512,8),
//    4 blocks/CU). Three changes:
//    1. W1 repacked pitch-6 v2f (pad 5->6, +90 fl): per-iter W = f4+f4+f2
//       (3 instr, was 5 b64). ocp*180 floats => 16B-aligned for all lanes.
//    2. conv2 W reads parity-split (i compile-time): even i f4,f4,f2 (3);
//       odd i f2,f4,f2,f2 (4). No repack, no LDS growth.
//    3. p1 stores f4+f4+f2 (3 instr, was 5 b64); base 48r+480oc aligned.
//  - LDS 10140 fl = 40560B; 4x40560 = 162240 <= 163840 -> 4 blocks/CU kept.
//  - Saved ~83 LDS instr/wave x32 waves ~= 19K cyc ~= 7.7us.
//    Predict dur 84 -> 76-78, VALU -> ~52%, conflicts ~0.7M, VGPR <= 64.
//    If unchanged -> LDS-issue model wrong; pivot or plateau.
// ---------------------------------------------------------------------------

typedef float v2f __attribute__((ext_vector_type(2)));
__device__ __forceinline__ v2f mk2(float a, float b) { v2f t; t.x = a; t.y = b; return t; }
__device__ __forceinline__ v2f shfl2(v2f v, int src) {
    v2f r; r.x = __shfl(v.x, src, 64); r.y = __shfl(v.y, src, 64); return r;
}

constexpr int THREADS = 512;
constexpr int IPB = 8;                 // images per block (1 per wave)

// LDS layout (float offsets)
constexpr int W1P_OFF = 0;             // conv1 w [ocp0..2][i0..14][kc0..5][2] = 540 (pitch-6 padded)
constexpr int W2P_OFF = 540;           // conv2 w packed [ocp0..7][k0..149][2] = 2400
constexpr int IMG_BASE = 2940;         // 16B-aligned (11760B)
// per-image offsets (region reused phase to phase):
constexpr int XS_OFF = 0;              // [3][15] rows of 20 fl (16 used) = 900
constexpr int P1_OFF = 0;              // [6][10][12] = 720 (overwrites xs)
constexpr int P2_OFF = 0;              // [400] (overwrites p1 head; wave-local dep)
constexpr int F1_OFF = 0;              // [120]
constexpr int F2_OFF = 128;            // [84]
constexpr int IMG_STRIDE = 900;
constexpr int LDS_FLOATS = IMG_BASE + IPB * IMG_STRIDE;   // 10140 -> 40560 B

__device__ __forceinline__ void wave_sync() {
    asm volatile("s_waitcnt lgkmcnt(0)" ::: "memory");
}

extern "C" __global__ __launch_bounds__(THREADS, 8)
void lenet_fused(const float* __restrict__ x,
                 const float* __restrict__ w1,
                 const float* __restrict__ w2,
                 const float* __restrict__ fc1w, const float* __restrict__ fc1b,
                 const float* __restrict__ fc2w, const float* __restrict__ fc2b,
                 const float* __restrict__ fc3w, const float* __restrict__ fc3b,
                 float* __restrict__ out)
{
    __shared__ __align__(16) float lds[LDS_FLOATS];
    const int tid  = threadIdx.x;
    const int lane = tid & 63;
    const int wv   = tid >> 6;          // 0..7, owns image wv
    const int img0 = blockIdx.x * IPB;
    const v2f zero2 = mk2(0.f, 0.f);

    // ---- stage conv1 weights, pitch-6 padded oc-pair-minor ----
    for (int i = tid; i < 540; i += THREADS) {
        int ocp = i / 180, rem = i - ocp * 180;
        int ii = rem / 12, kh = rem - ii * 12, kc = kh >> 1, h = kh & 1;
        lds[W1P_OFF + i] = (kc < 5) ? w1[(2 * ocp + h) * 75 + ii * 5 + kc] : 0.f;
    }
    // ---- stage conv2 weights, oc-pair-minor (unpadded) ----
    for (int i = tid; i < 2400; i += THREADS) {
        int ocp = i / 300, rem = i - ocp * 300, k = rem >> 1, h = rem & 1;
        lds[W2P_OFF + i] = w2[(2 * ocp + h) * 150 + k];
    }

    // ---- stage input patch rows 0..14, cols 0..15 into 20-fl rows ----
    float* base = lds + IMG_BASE + wv * IMG_STRIDE;
    {
        const float4* xg = (const float4*)(x + (size_t)(img0 + wv) * 3072);
        float4* d = (float4*)(base + XS_OFF);
        for (int i = lane; i < 180; i += 64) {       // 3ch * 15r * 4(f4)
            int c = i / 60, rem = i - c * 60;
            int r = rem >> 2, c4 = rem & 3;
            d[c * 75 + r * 5 + c4] = xg[c * 256 + r * 8 + c4];   // 20-fl row pitch
        }
    }
    __syncthreads();   // weights + staging visible

    float* p1 = base + P1_OFF;

    // ---- conv1 + relu + pool1 -> p1 [6][10][12] ----
    // lane -> (ocp 0..2, r 0..10); 33 active, dup lanes guarded at store.
    {
        const int l   = (lane < 33) ? lane : 32;
        const int ocp = l / 11;
        const int r   = l - ocp * 11;
        const float4* xs = (const float4*)(base + XS_OFF);

        v2f acc[11];
        #pragma unroll
        for (int c = 0; c < 11; ++c) acc[c] = zero2;

        #pragma unroll
        for (int i = 0; i < 15; ++i) {
            const int ci = i / 5, kr = i - ci * 5;
            const int b = ci * 75 + (r + kr) * 5;    // 20-fl rows: 5 f4 pitch
            float4 A0 = xs[b], A1 = xs[b + 1], A2 = xs[b + 2], A3 = xs[b + 3];
            // W taps: pitch-6 v2f block, 16B-aligned for every ocp -> f4,f4,f2
            const float* w1f = lds + W1P_OFF + ocp * 180 + i * 12;
            float4 q0 = *(const float4*)(w1f);
            float4 q1 = *(const float4*)(w1f + 4);
            float2 q2 = *(const float2*)(w1f + 8);
            v2f W[5];
            W[0] = mk2(q0.x, q0.y); W[1] = mk2(q0.z, q0.w);
            W[2] = mk2(q1.x, q1.y); W[3] = mk2(q1.z, q1.w);
            W[4] = mk2(q2.x, q2.y);
            float xa[16];
            xa[0]=A0.x; xa[1]=A0.y; xa[2]=A0.z;  xa[3]=A0.w;
            xa[4]=A1.x; xa[5]=A1.y; xa[6]=A1.z;  xa[7]=A1.w;
            xa[8]=A2.x; xa[9]=A2.y; xa[10]=A2.z; xa[11]=A2.w;
            xa[12]=A3.x; xa[13]=A3.y; xa[14]=A3.z; xa[15]=A3.w;
            #pragma unroll
            for (int kc = 0; kc < 5; ++kc) {
                #pragma unroll
                for (int c = 0; c < 11; ++c) {
                    acc[c] = __builtin_elementwise_fma(
                        mk2(xa[c + kc], xa[c + kc]), W[kc], acc[c]);
                }
            }
        }

        // relu + 2x2 stride-1 pool (packed over oc pair)
        v2f pm[10], m[10];
        #pragma unroll
        for (int c = 0; c < 10; ++c) {
            v2f a0 = __builtin_elementwise_max(acc[c], zero2);
            v2f a1 = __builtin_elementwise_max(acc[c + 1], zero2);
            pm[c] = __builtin_elementwise_max(a0, a1);
        }
        #pragma unroll
        for (int c = 0; c < 10; ++c)
            m[c] = __builtin_elementwise_max(pm[c], shfl2(pm[c], lane + 1));
        wave_sync();   // xs reads drained before overwriting region with p1
        if (r < 10) {
            const int oc0 = ocp * 2;
            float* d0 = p1 + oc0 * 120 + r * 12;        // 48r+480oc: 16B-aligned
            float* d1 = p1 + (oc0 + 1) * 120 + r * 12;
            *(float4*)(d0)     = make_float4(m[0].x, m[1].x, m[2].x, m[3].x);
            *(float4*)(d0 + 4) = make_float4(m[4].x, m[5].x, m[6].x, m[7].x);
            *(float2*)(d0 + 8) = make_float2(m[8].x, m[9].x);
            *(float4*)(d1)     = make_float4(m[0].y, m[1].y, m[2].y, m[3].y);
            *(float4*)(d1 + 4) = make_float4(m[4].y, m[5].y, m[6].y, m[7].y);
            *(float2*)(d1 + 8) = make_float2(m[8].y, m[9].y);
        }
    }
    wave_sync();

    // ---- conv2 + relu + pool2 -> p2 [16*5*5] flatten order ----
    float* p2 = base + P2_OFF;
    {
        const int l   = (lane < 48) ? lane : 47;
        const int ocp = l / 6;
        const int r   = l - ocp * 6;
        const float4* pa4 = (const float4*)p1;
        const float2* pa2 = (const float2*)p1;

        v2f acc[6];
        #pragma unroll
        for (int c = 0; c < 6; ++c) acc[c] = zero2;

        #pragma unroll
        for (int i = 0; i < 30; ++i) {
            const int ci = i / 5, kr = i - ci * 5;
            float4 A0 = pa4[ci * 30 + (r + kr) * 3 + 0];
            float4 A1 = pa4[ci * 30 + (r + kr) * 3 + 1];
            float2 A2 = pa2[ci * 60 + (r + kr) * 6 + 4];
            // W taps at float base ocp*300 + i*10: parity of i decides shape
            // (i is compile-time under full unroll; ocp*300 keeps it lane-uniform)
            const float* w2f = lds + W2P_OFF + ocp * 300 + i * 10;
            v2f W[5];
            if ((i & 1) == 0) {
                float4 q0 = *(const float4*)(w2f);
                float4 q1 = *(const float4*)(w2f + 4);
                float2 q2 = *(const float2*)(w2f + 8);
                W[0] = mk2(q0.x, q0.y); W[1] = mk2(q0.z, q0.w);
                W[2] = mk2(q1.x, q1.y); W[3] = mk2(q1.z, q1.w);
                W[4] = mk2(q2.x, q2.y);
            } else {
                float2 r0 = *(const float2*)(w2f);
                float4 r1 = *(const float4*)(w2f + 2);
                float2 r2 = *(const float2*)(w2f + 6);
                float2 r3 = *(const float2*)(w2f + 8);
                W[0] = mk2(r0.x, r0.y); W[1] = mk2(r1.x, r1.y);
                W[2] = mk2(r1.z, r1.w); W[3] = mk2(r2.x, r2.y);
                W[4] = mk2(r3.x, r3.y);
            }
            float xa[10];
            xa[0]=A0.x; xa[1]=A0.y; xa[2]=A0.z; xa[3]=A0.w;
            xa[4]=A1.x; xa[5]=A1.y; xa[6]=A1.z; xa[7]=A1.w;
            xa[8]=A2.x; xa[9]=A2.y;
            #pragma unroll
            for (int kc = 0; kc < 5; ++kc) {
                #pragma unroll
                for (int c = 0; c < 6; ++c) {
                    acc[c] = __builtin_elementwise_fma(
                        mk2(xa[c + kc], xa[c + kc]), W[kc], acc[c]);
                }
            }
        }

        v2f pm[5], m[5];
        #pragma unroll
        for (int c = 0; c < 5; ++c) {
            v2f a0 = __builtin_elementwise_max(acc[c], zero2);
            v2f a1 = __builtin_elementwise_max(acc[c + 1], zero2);
            pm[c] = __builtin_elementwise_max(a0, a1);
        }
        #pragma unroll
        for (int c = 0; c < 5; ++c)
            m[c] = __builtin_elementwise_max(pm[c], shfl2(pm[c], lane + 1));
        wave_sync();   // p1 reads drained before overwriting head with p2
        if (r < 5) {
            const int oc0 = ocp * 2;
            #pragma unroll
            for (int c = 0; c < 5; ++c) {
                p2[oc0 * 25 + r * 5 + c]       = m[c].x;
                p2[(oc0 + 1) * 25 + r * 5 + c] = m[c].y;
            }
        }
    }
    __syncthreads();   // all 8 images' p2 ready; weight region becomes scratch

    // ---- fc1 (120x400) 480 thr: (row, Khalf, imh), 4 images per thread ----
    float* scr = lds;   // [8][240] = 1920 floats over dead weight region
    if (tid < 480) {
        const int row  = tid >> 2;
        const int rh   = tid & 3;
        const int half = rh >> 1;
        const int imh  = rh & 1;       // images imh*4 .. imh*4+3
        const float4* wrow = (const float4*)(fc1w + row * 400) + half * 50;
        v2f acc[4];
        #pragma unroll
        for (int q = 0; q < 4; ++q) acc[q] = zero2;
        #pragma unroll 2
        for (int k = 0; k < 50; ++k) {
            float4 w4 = wrow[k];
            const v2f wxy = mk2(w4.x, w4.y), wzw = mk2(w4.z, w4.w);
            #pragma unroll
            for (int q = 0; q < 4; ++q) {
                const float4* ap = (const float4*)(lds + IMG_BASE + (imh * 4 + q) * IMG_STRIDE + P2_OFF) + half * 50;
                float4 a = ap[k];
                acc[q] = __builtin_elementwise_fma(mk2(a.x, a.y), wxy, acc[q]);
                acc[q] = __builtin_elementwise_fma(mk2(a.z, a.w), wzw, acc[q]);
            }
        }
        #pragma unroll
        for (int q = 0; q < 4; ++q)
            scr[(imh * 4 + q) * 240 + row * 2 + half] = acc[q].x + acc[q].y;
    }
    __syncthreads();

    // ---- fc1 reduce + bias + relu -> f1 per image ----
    if (tid < 120) {
        const float b = fc1b[tid];
        #pragma unroll
        for (int im = 0; im < 8; ++im) {
            float v = scr[im * 240 + tid * 2] + scr[im * 240 + tid * 2 + 1] + b;
            lds[IMG_BASE + im * IMG_STRIDE + F1_OFF + tid] = fmaxf(v, 0.f);
        }
    }
    __syncthreads();

    // ---- fc2 (84x120) + relu, 168 thr: (row, imh), 4 images per thread ----
    if (tid < 168) {
        const int row = tid >> 1;
        const int imh = tid & 1;
        const float4* wrow = (const float4*)(fc2w + row * 120);
        const float bz = fc2b[row];
        v2f acc[4];
        #pragma unroll
        for (int q = 0; q < 4; ++q) acc[q] = zero2;
        #pragma unroll 2
        for (int k = 0; k < 30; ++k) {
            float4 w4 = wrow[k];
            const v2f wxy = mk2(w4.x, w4.y), wzw = mk2(w4.z, w4.w);
            #pragma unroll
            for (int q = 0; q < 4; ++q) {
                const float4* fp = (const float4*)(lds + IMG_BASE + (imh * 4 + q) * IMG_STRIDE + F1_OFF);
                float4 a = fp[k];
                acc[q] = __builtin_elementwise_fma(mk2(a.x, a.y), wxy, acc[q]);
                acc[q] = __builtin_elementwise_fma(mk2(a.z, a.w), wzw, acc[q]);
            }
        }
        #pragma unroll
        for (int q = 0; q < 4; ++q)
            lds[IMG_BASE + (imh * 4 + q) * IMG_STRIDE + F2_OFF + row] =
                fmaxf(acc[q].x + acc[q].y + bz, 0.f);
    }
    __syncthreads();

    // ---- fc3 (10x84) -> out, 8 images x 10 rows = 80 threads ----
    if (tid < 80) {
        const int im  = tid / 10;
        const int row = tid - im * 10;
        const float4* wrow = (const float4*)(fc3w + row * 84);
        const float4* f2 = (const float4*)(lds + IMG_BASE + im * IMG_STRIDE + F2_OFF);
        v2f acc = zero2;
        #pragma unroll
        for (int k = 0; k < 21; ++k) {
            float4 w4 = wrow[k];
            float4 a = f2[k];
            acc = __builtin_elementwise_fma(mk2(a.x, a.y), mk2(w4.x, w4.y), acc);
            acc = __builtin_elementwise_fma(mk2(a.z, a.w), mk2(w4.z, w4.w), acc);
        }
        out[(size_t)(img0 + im) * 10 + row] = acc.x + acc.y + fc3b[row];
    }
}

extern "C" void kernel_launch(void* const* d_in, const int* in_sizes, int n_in,
                              void* d_out, int out_size, void* d_ws, size_t ws_size,
                              hipStream_t stream) {
    const float* x    = (const float*)d_in[0];
    const float* w1   = (const float*)d_in[1];
    const float* w2   = (const float*)d_in[2];
    const float* fc1w = (const float*)d_in[3];
    const float* fc1b = (const float*)d_in[4];
    const float* fc2w = (const float*)d_in[5];
    const float* fc2b = (const float*)d_in[6];
    const float* fc3w = (const float*)d_in[7];
    const float* fc3b = (const float*)d_in[8];
    float* out = (float*)d_out;

    const int B = in_sizes[0] / 3072;       // 8192
    const int grid = B / IPB;               // 1024
    lenet_fused<<<grid, THREADS, 0, stream>>>(x, w1, w2, fc1w, fc1b,
                                              fc2w, fc2b, fc3w, fc3b, out);
}